// Round 8
// baseline (447.642 us; speedup 1.0000x reference)
//
#include <hip/hip_runtime.h>
#include <hip/hip_bf16.h>

#define SEQ 120
#define CELLS 30          // real cells (ci<5); row ci=5 is pad-only, precomputed
#define RDIM 48
#define BQ 4096
#define MTOT (BQ*CELLS)           // 122880
#define MAIN_BLOCKS (MTOT/64)     // 1920
#define ASTRIDE 1040              // 1024 + 16B pad: rotates bank-group per row
#define ABUF 66560                // 64 * 1040

typedef __bf16 bf16x8 __attribute__((ext_vector_type(8)));
typedef float  f32x4  __attribute__((ext_vector_type(4)));

__device__ __forceinline__ float gelu_f(float x){
  return 0.5f * x * (1.0f + erff(x * 0.7071067811865476f));
}
__device__ __forceinline__ bf16x8 pack8(f32x4 a, f32x4 b){
  bf16x8 r;
  r[0]=(__bf16)a[0]; r[1]=(__bf16)a[1]; r[2]=(__bf16)a[2]; r[3]=(__bf16)a[3];
  r[4]=(__bf16)b[0]; r[5]=(__bf16)b[1]; r[6]=(__bf16)b[2]; r[7]=(__bf16)b[3];
  return r;
}

// ---------------- prep: weight repack (fp32->bf16) + pad-cell readout Gpad ----------------
__global__ void prep_kernel(const float* __restrict__ conv_w, const float* __restrict__ conv_b,
                            const float* __restrict__ P,
                            const float* __restrict__ red_w, const float* __restrict__ red_b,
                            const float* __restrict__ res_w1, const float* __restrict__ res_w2,
                            __bf16* __restrict__ W_bt, __bf16* __restrict__ W_red,
                            __bf16* __restrict__ W1p, __bf16* __restrict__ W2p,
                            float* __restrict__ Gpad)
{
  const int b = blockIdx.x, t = threadIdx.x;
  if (b < 256){
    // W_bt[o][k], k = pos*256 + c  (pos = kh*2+kw)
    #pragma unroll
    for (int u=0;u<4;u++){
      int k = u*256 + t;
      W_bt[b*1024 + k] = (__bf16)conv_w[b*1024 + (k&255)*4 + (k>>8)];
    }
  } else if (b == 256){
    for (int i=t; i<48*256; i+=256) W_red[i] = (__bf16)red_w[i];
  } else if (b < 273){
    int l = b - 257;
    #pragma unroll
    for (int u=0;u<12;u++){
      int idx = u*256 + t;               // j*64 + k
      int j = idx >> 6, k = idx & 63;
      W1p[l*3072 + idx] = (k < 48) ? (__bf16)res_w1[(l*48+j)*48 + k] : (__bf16)0.0f;
    }
  } else if (b < 289){
    int l = b - 273;
    #pragma unroll
    for (int u=0;u<12;u++){
      int idx = u*256 + t;
      int j = idx >> 6, k = idx & 63;
      W2p[l*3072 + idx] = (k < 48) ? (__bf16)res_w2[(l*48+j)*48 + k] : (__bf16)0.0f;
    }
  } else {
    // Gpad: full fp32 readout of the all-pad patch (all 4 positions = P)
    __shared__ float tg[256];
    float z = conv_b[t];
    for (int c=0;c<256;c++){
      const float* w = conv_w + t*1024 + c*4;
      z += (w[0]+w[1]+w[2]+w[3]) * P[c];
    }
    tg[t] = gelu_f(z);
    __syncthreads();
    if (t < 48){
      float g = red_b[t];
      for (int o=0;o<256;o++) g += red_w[t*256+o]*tg[o];
      Gpad[t] = gelu_f(g);
    }
  }
}

// ---------------- main: position-granular gll-staged patch-GEMM (M=122880,N=256,K=1024)
//                  Every HBM read = one full 1KB contiguous token (DRAM-page friendly).
//                  4 phases (BK=256). A f32 token-major dbuf in LDS; B per-wave from L2.
//                  + gelu + fused 256->48 GEMM + gelu -> G ----------------
__global__ __launch_bounds__(512, 2) void main_kernel(
    const float* __restrict__ X, const __bf16* __restrict__ W_bt,
    const float* __restrict__ conv_b, const __bf16* __restrict__ W_red,
    const float* __restrict__ red_b, float* __restrict__ G)
{
  // LDS: A f32 dbuf [2][64 rows][1040B] = 130KB; Y bf16 [64][512B]=32KB reuses buf0 region
  __shared__ __align__(16) char sm[2*ABUF];
  const int tid  = threadIdx.x;
  const int lane = tid & 63;
  const int wave = tid >> 6;                 // 0..7; wave grid 2(M) x 4(N)
  const int wm = wave >> 2, wn = wave & 3;
  const int lr = lane & 15, lk = lane >> 4;
  const int m0 = blockIdx.x * 64;

  // A staging: gll j of wave w stages row j*8+w's token(p): 1KB CONTIGUOUS (lane*16B)
  const char* rowsrc[8];
  #pragma unroll
  for (int j=0;j<8;j++){
    int row = j*8 + wave;
    int m = m0 + row;
    int bs = m / 30;
    int cs = m - bs*30;
    int ci = cs/6, cj = cs - ci*6;           // ci<5 => all 4 tokens < 120
    rowsrc[j] = (const char*)(X + ((size_t)bs*SEQ + 24*ci + 2*cj)*256) + lane*16;
  }
  const __bf16* bbase[4];
  #pragma unroll
  for (int ni=0; ni<4; ++ni)
    bbase[ni] = W_bt + (size_t)(wn*64 + ni*16 + lr)*1024 + lk*8;

  f32x4 acc[2][4];
  #pragma unroll
  for (int a=0;a<2;a++)
    #pragma unroll
    for (int b=0;b<4;b++) acc[a][b] = (f32x4){0.f,0.f,0.f,0.f};

  // token byte-offset for position p: ((p>>1)*12 + (p&1)) * 1024
  auto STAGE = [&](int p, int d){
    const int goff = (((p>>1)*12 + (p&1)) << 10);
    #pragma unroll
    for (int j=0;j<8;j++){
      __builtin_amdgcn_global_load_lds(
        (const __attribute__((address_space(1))) void*)(rowsrc[j] + goff),
        (__attribute__((address_space(3))) void*)(sm + d*ABUF + (j*8 + wave)*ASTRIDE),
        16, 0, 0);
    }
  };

  STAGE(0, 0);
  __syncthreads();                            // drain: A(0) resident for all waves

  for (int p=0; p<4; ++p){
    const int buf = (p&1)*ABUF;
    if (p < 3) STAGE(p+1, (p+1)&1);           // issue early; forced complete by this
                                              // phase's end-of-phase __syncthreads drain
    #pragma unroll
    for (int ck=0; ck<4; ++ck){
      #pragma unroll
      for (int ks=0; ks<2; ++ks){
        bf16x8 bv[4];
        #pragma unroll
        for (int ni=0; ni<4; ++ni)
          bv[ni] = *(const bf16x8*)(bbase[ni] + p*256 + ck*64 + ks*32);
        bf16x8 av[2];
        #pragma unroll
        for (int mi=0; mi<2; ++mi){
          int row = wm*32 + mi*16 + lr;
          const char* base = sm + buf + row*ASTRIDE + ck*256 + ks*128 + lk*32;
          f32x4 u0 = *(const f32x4*)(base);
          f32x4 u1 = *(const f32x4*)(base + 16);
          av[mi] = pack8(u0,u1);
        }
        #pragma unroll
        for (int mi=0; mi<2; ++mi)
          #pragma unroll
          for (int ni=0; ni<4; ++ni)
            acc[mi][ni] = __builtin_amdgcn_mfma_f32_16x16x32_bf16(av[mi], bv[ni], acc[mi][ni], 0,0,0);
      }
    }
    __syncthreads();                          // vmcnt(0)-drain + barrier: dbuf handoff
  }

  // epilogue 1: conv bias + gelu -> Y bf16 [64][512B] in LDS (row-swizzled), reuses buf0 region
  #pragma unroll
  for (int ni=0; ni<4; ++ni){
    const int col = wn*64 + ni*16 + lr;
    const float cb = conv_b[col];
    #pragma unroll
    for (int mi=0; mi<2; ++mi){
      #pragma unroll
      for (int reg=0; reg<4; ++reg){
        int row = wm*32 + mi*16 + lk*4 + reg;
        float y = gelu_f(acc[mi][ni][reg] + cb);
        *(__bf16*)(sm + ((row*512 + col*2) ^ ((row&7)<<4))) = (__bf16)y;
      }
    }
  }
  __syncthreads();

  // GEMM2: G = gelu(Y @ red_w^T + red_b); waves 0..3, wave w owns rows [w*16, w*16+16)
  if (wave < 4){
    f32x4 acc2[3];
    #pragma unroll
    for (int nf=0;nf<3;nf++) acc2[nf] = (f32x4){0.f,0.f,0.f,0.f};
    const int rowY = wave*16 + lr;
    const int keyY = (rowY&7)<<4;
    #pragma unroll
    for (int kk=0; kk<8; ++kk){
      bf16x8 a2 = *(const bf16x8*)(sm + ((rowY*512 + kk*64 + lk*16) ^ keyY));
      #pragma unroll
      for (int nf=0; nf<3; ++nf){
        bf16x8 b2 = *(const bf16x8*)(W_red + (size_t)(nf*16+lr)*256 + kk*32 + lk*8);
        acc2[nf] = __builtin_amdgcn_mfma_f32_16x16x32_bf16(a2, b2, acc2[nf], 0,0,0);
      }
    }
    #pragma unroll
    for (int nf=0; nf<3; ++nf){
      float rb = red_b[nf*16+lr];
      #pragma unroll
      for (int reg=0; reg<4; ++reg){
        int grow = m0 + wave*16 + lk*4 + reg;
        G[(size_t)grow*RDIM + nf*16 + lr] = gelu_f(acc2[nf][reg] + rb);
      }
    }
  }
}

// ---------------- head: pool + 16 residual blocks (bf16 MFMA, K padded to 64) + linear ----------------
__global__ __launch_bounds__(64) void head_kernel(
    const float* __restrict__ G, const float* __restrict__ Gpad,
    const __bf16* __restrict__ W1p, const __bf16* __restrict__ W2p,
    const float* __restrict__ res_b1, const float* __restrict__ res_b2,
    const float* __restrict__ out_w, const float* __restrict__ out_b,
    float* __restrict__ out)
{
  __shared__ __align__(16) char Hs[16*256];  // [16 rows][64 f32], swizzled, cols 48..63 = 0
  __shared__ __align__(16) char Ys[16*256];
  const int t = threadIdx.x;                 // one wave
  const int lr = t & 15, lk = t >> 4;
  const int b0 = blockIdx.x * 16;

  { // zero pad cols 48..63 (stay zero: layers only write cols<48)
    int row = t >> 2, j4 = 12 + (t & 3);
    int off = (row*256 + j4*16) ^ ((row&7)<<5);
    *(f32x4*)(Hs + off) = (f32x4){0,0,0,0};
    *(f32x4*)(Ys + off) = (f32x4){0,0,0,0};
  }

  // pool: H[b][j] = (sum_{c<30} G[b][c][j] + 6*Gpad[j]) / 36
  #pragma unroll
  for (int pp=0; pp<3; ++pp){
    int idx = pp*64 + t;
    int b = idx / 12, j4 = idx - b*12;
    f32x4 s = ((const f32x4*)Gpad)[j4] * 6.0f;
    const float* g = G + ((size_t)(b0+b)*CELLS)*RDIM + j4*4;
    #pragma unroll
    for (int c=0;c<CELLS;c++) s += *(const f32x4*)(g + c*RDIM);
    s *= (1.0f/36.0f);
    *(f32x4*)(Hs + ((b*256 + j4*16) ^ ((b&7)<<5))) = s;
  }
  __syncthreads();

  const int rowA = lr;
  const int keyA = (rowA&7)<<5;
  for (int l=0; l<16; ++l){
    bf16x8 a[2];
    #pragma unroll
    for (int kk=0;kk<2;kk++){
      f32x4 u0 = *(const f32x4*)(Hs + ((rowA*256 + kk*128 + lk*32) ^ keyA));
      f32x4 u1 = *(const f32x4*)(Hs + ((rowA*256 + kk*128 + lk*32 + 16) ^ keyA));
      a[kk] = pack8(u0,u1);
    }
    #pragma unroll
    for (int nf=0; nf<3; ++nf){
      f32x4 acc = (f32x4){0,0,0,0};
      #pragma unroll
      for (int kk=0;kk<2;kk++){
        bf16x8 bw = *(const bf16x8*)(W1p + ((size_t)l*48 + nf*16 + lr)*64 + kk*32 + lk*8);
        acc = __builtin_amdgcn_mfma_f32_16x16x32_bf16(a[kk], bw, acc, 0,0,0);
      }
      float bj = res_b1[l*48 + nf*16 + lr];
      #pragma unroll
      for (int reg=0; reg<4; ++reg){
        int row = lk*4 + reg;
        *(float*)(Ys + ((row*256 + (nf*16+lr)*4) ^ ((row&7)<<5))) = gelu_f(acc[reg] + bj);
      }
    }
    __syncthreads();
    bf16x8 a2[2];
    #pragma unroll
    for (int kk=0;kk<2;kk++){
      f32x4 u0 = *(const f32x4*)(Ys + ((rowA*256 + kk*128 + lk*32) ^ keyA));
      f32x4 u1 = *(const f32x4*)(Ys + ((rowA*256 + kk*128 + lk*32 + 16) ^ keyA));
      a2[kk] = pack8(u0,u1);
    }
    #pragma unroll
    for (int nf=0; nf<3; ++nf){
      f32x4 acc = (f32x4){0,0,0,0};
      #pragma unroll
      for (int kk=0;kk<2;kk++){
        bf16x8 bw = *(const bf16x8*)(W2p + ((size_t)l*48 + nf*16 + lr)*64 + kk*32 + lk*8);
        acc = __builtin_amdgcn_mfma_f32_16x16x32_bf16(a2[kk], bw, acc, 0,0,0);
      }
      float bj = res_b2[l*48 + nf*16 + lr];
      #pragma unroll
      for (int reg=0; reg<4; ++reg){
        int row = lk*4 + reg;
        float* hp = (float*)(Hs + ((row*256 + (nf*16+lr)*4) ^ ((row&7)<<5)));
        *hp += acc[reg] + bj;
      }
    }
    __syncthreads();
  }

  float s = 0.f;
  #pragma unroll
  for (int i=0;i<12;i++){
    int j = lk*12 + i;
    s += *(const float*)(Hs + ((lr*256 + j*4) ^ ((lr&7)<<5))) * out_w[j];
  }
  s += __shfl_xor(s, 16);
  s += __shfl_xor(s, 32);
  if (lk == 0) out[b0 + lr] = s + out_b[0];
}

extern "C" void kernel_launch(void* const* d_in, const int* in_sizes, int n_in,
                              void* d_out, int out_size, void* d_ws, size_t ws_size,
                              hipStream_t stream) {
  const float* X      = (const float*)d_in[0];
  const float* P      = (const float*)d_in[1];
  const float* conv_w = (const float*)d_in[2];
  const float* conv_b = (const float*)d_in[3];
  const float* red_w  = (const float*)d_in[4];
  const float* red_b  = (const float*)d_in[5];
  const float* res_w1 = (const float*)d_in[6];
  const float* res_b1 = (const float*)d_in[7];
  const float* res_w2 = (const float*)d_in[8];
  const float* res_b2 = (const float*)d_in[9];
  const float* out_w  = (const float*)d_in[10];
  const float* out_b  = (const float*)d_in[11];
  float* out = (float*)d_out;

  char* ws = (char*)d_ws;
  __bf16* W_bt  = (__bf16*)(ws);             // 524288 B
  __bf16* W_red = (__bf16*)(ws + 524288);    // 24576 B
  __bf16* W1p   = (__bf16*)(ws + 548864);    // 98304 B
  __bf16* W2p   = (__bf16*)(ws + 647168);    // 98304 B
  float*  Gpad  = (float*)(ws + 745472);     // 192 B
  float*  G     = (float*)(ws + 1048576);    // 23.6 MB

  prep_kernel<<<290, 256, 0, stream>>>(conv_w, conv_b, P, red_w, red_b, res_w1, res_w2,
                                       W_bt, W_red, W1p, W2p, Gpad);
  main_kernel<<<MAIN_BLOCKS, 512, 0, stream>>>(X, W_bt, conv_b, W_red, red_b, G);
  head_kernel<<<BQ/16, 64, 0, stream>>>(G, Gpad, W1p, W2p, res_b1, res_b2, out_w, out_b, out);
}

// Round 10
// 382.796 us; speedup vs baseline: 1.1694x; 1.1694x over previous
//
#include <hip/hip_runtime.h>
#include <hip/hip_bf16.h>

#define SEQ 120
#define CELLS 30          // real cells (ci<5); row ci=5 is pad-only, precomputed
#define RDIM 48
#define BQ 4096
#define MTOT (BQ*CELLS)           // 122880
#define MAIN_BLOCKS (MTOT/32)     // 3840
#define ASTRIDE 2064              // 2048 + 16: 16B-aligned, rows rotate 4 banks -> 2-way (free)

typedef __bf16 bf16x8 __attribute__((ext_vector_type(8)));
typedef float  f32x4  __attribute__((ext_vector_type(4)));

__device__ __forceinline__ float gelu_f(float x){
  return 0.5f * x * (1.0f + erff(x * 0.7071067811865476f));
}
__device__ __forceinline__ bf16x8 pack8(f32x4 a, f32x4 b){
  bf16x8 r;
  r[0]=(__bf16)a[0]; r[1]=(__bf16)a[1]; r[2]=(__bf16)a[2]; r[3]=(__bf16)a[3];
  r[4]=(__bf16)b[0]; r[5]=(__bf16)b[1]; r[6]=(__bf16)b[2]; r[7]=(__bf16)b[3];
  return r;
}

// ---------------- prep: weight repack (fp32->bf16) + pad-cell readout Gpad ----------------
__global__ void prep_kernel(const float* __restrict__ conv_w, const float* __restrict__ conv_b,
                            const float* __restrict__ P,
                            const float* __restrict__ red_w, const float* __restrict__ red_b,
                            const float* __restrict__ res_w1, const float* __restrict__ res_w2,
                            __bf16* __restrict__ W_bt, __bf16* __restrict__ W_red,
                            __bf16* __restrict__ W1p, __bf16* __restrict__ W2p,
                            float* __restrict__ Gpad)
{
  const int b = blockIdx.x, t = threadIdx.x;
  if (b < 256){
    // W_bt[o][k], k = pos*256 + c  (pos = kh*2+kw)
    #pragma unroll
    for (int u=0;u<4;u++){
      int k = u*256 + t;
      W_bt[b*1024 + k] = (__bf16)conv_w[b*1024 + (k&255)*4 + (k>>8)];
    }
  } else if (b == 256){
    for (int i=t; i<48*256; i+=256) W_red[i] = (__bf16)red_w[i];
  } else if (b < 273){
    int l = b - 257;
    #pragma unroll
    for (int u=0;u<12;u++){
      int idx = u*256 + t;               // j*64 + k
      int j = idx >> 6, k = idx & 63;
      W1p[l*3072 + idx] = (k < 48) ? (__bf16)res_w1[(l*48+j)*48 + k] : (__bf16)0.0f;
    }
  } else if (b < 289){
    int l = b - 273;
    #pragma unroll
    for (int u=0;u<12;u++){
      int idx = u*256 + t;
      int j = idx >> 6, k = idx & 63;
      W2p[l*3072 + idx] = (k < 48) ? (__bf16)res_w2[(l*48+j)*48 + k] : (__bf16)0.0f;
    }
  } else {
    // Gpad: full fp32 readout of the all-pad patch (all 4 positions = P)
    __shared__ float tg[256];
    float z = conv_b[t];
    for (int c=0;c<256;c++){
      const float* w = conv_w + t*1024 + c*4;
      z += (w[0]+w[1]+w[2]+w[3]) * P[c];
    }
    tg[t] = gelu_f(z);
    __syncthreads();
    if (t < 48){
      float g = red_b[t];
      for (int o=0;o<256;o++) g += red_w[t*256+o]*tg[o];
      Gpad[t] = gelu_f(g);
    }
  }
}

// ---------------- main: 2-phase (position-pair) gll-staged patch-GEMM (M=122880,N=256,K=1024)
//   Phase = tokens {t0+12ph, t0+12ph+1}: each row's stage = 2KB CONTIGUOUS; rows tile into
//   ~12KB contiguous spans (DRAM-channel friendly). Stage fully drained before compute
//   (no vmcnt FIFO coupling with compute's L2 B-loads); stall covered by 2 blocks/CU TLP.
//   + gelu + fused 256->48 GEMM + gelu -> G ----------------
__global__ __launch_bounds__(256, 2) void main_kernel(
    const float* __restrict__ X, const __bf16* __restrict__ W_bt,
    const float* __restrict__ conv_b, const __bf16* __restrict__ W_red,
    const float* __restrict__ red_b, float* __restrict__ G)
{
  // LDS: A f32 [32 rows][2064B] = 66048B single buffer; Y bf16 [32][512B]=16KB reuses head
  __shared__ __align__(16) char sm[32*ASTRIDE];
  const int tid  = threadIdx.x;
  const int lane = tid & 63;
  const int wave = tid >> 6;                 // 0..3 = N-quadrant (64 cols each)
  const int lr = lane & 15, lk = lane >> 4;
  const int m0 = blockIdx.x * 32;

  // stage geometry: wave w, rows w*8 .. w*8+7; per row 2 gll (halves), 1KB contiguous each
  const char* rowsrc[8];
  #pragma unroll
  for (int j=0;j<8;j++){
    int row = wave*8 + j;
    int m = m0 + row;
    int bs = m / 30;
    int cs = m - bs*30;
    int ci = cs/6, cj = cs - ci*6;           // ci<5 => tokens t0..t0+13 all < 120
    rowsrc[j] = (const char*)(X + ((size_t)bs*SEQ + 24*ci + 2*cj)*256) + lane*16;
  }
  const __bf16* bbase[4];
  #pragma unroll
  for (int ni=0; ni<4; ++ni)
    bbase[ni] = W_bt + (size_t)(wave*64 + ni*16 + lr)*1024 + lk*8;

  f32x4 acc[2][4];
  #pragma unroll
  for (int a=0;a<2;a++)
    #pragma unroll
    for (int b=0;b<4;b++) acc[a][b] = (f32x4){0.f,0.f,0.f,0.f};

  // stage phase ph: 16 gll per wave; row's 2KB contiguous from X (tokens t0+12ph, +1)
  auto STAGE = [&](int ph){
    const int goff = ph*12288;               // 12 tokens * 1024B
    #pragma unroll
    for (int j=0;j<8;j++){
      #pragma unroll
      for (int h=0;h<2;h++){
        __builtin_amdgcn_global_load_lds(
          (const __attribute__((address_space(1))) void*)(rowsrc[j] + goff + h*1024),
          (__attribute__((address_space(3))) void*)(sm + (wave*8+j)*ASTRIDE + h*1024),
          16, 0, 0);
      }
    }
  };

  for (int ph=0; ph<2; ++ph){
    STAGE(ph);
    __syncthreads();                         // vmcnt(0) drain + barrier: A(ph) resident
    #pragma unroll
    for (int ls=0; ls<8; ++ls){              // k = ph*512 + ls*64 + ks*32
      #pragma unroll
      for (int ks=0; ks<2; ++ks){
        bf16x8 bv[4];
        #pragma unroll
        for (int ni=0; ni<4; ++ni)
          bv[ni] = *(const bf16x8*)(bbase[ni] + ph*512 + ls*64 + ks*32);
        bf16x8 av[2];
        #pragma unroll
        for (int mi=0; mi<2; ++mi){
          int row = mi*16 + lr;
          const char* base = sm + row*ASTRIDE + ls*256 + ks*128 + lk*32;
          f32x4 u0 = *(const f32x4*)(base);
          f32x4 u1 = *(const f32x4*)(base + 16);
          av[mi] = pack8(u0,u1);
        }
        #pragma unroll
        for (int mi=0; mi<2; ++mi)
          #pragma unroll
          for (int ni=0; ni<4; ++ni)
            acc[mi][ni] = __builtin_amdgcn_mfma_f32_16x16x32_bf16(av[mi], bv[ni], acc[mi][ni], 0,0,0);
      }
    }
    __syncthreads();                         // all waves done reading A(ph) before overwrite
  }

  // epilogue 1: conv bias + gelu -> Y bf16 [32][512B] in LDS (row-swizzled), reuses A region
  #pragma unroll
  for (int ni=0; ni<4; ++ni){
    const int col = wave*64 + ni*16 + lr;
    const float cb = conv_b[col];
    #pragma unroll
    for (int mi=0; mi<2; ++mi){
      #pragma unroll
      for (int reg=0; reg<4; ++reg){
        int row = mi*16 + lk*4 + reg;
        float y = gelu_f(acc[mi][ni][reg] + cb);
        *(__bf16*)(sm + ((row*512 + col*2) ^ ((row&7)<<4))) = (__bf16)y;
      }
    }
  }
  __syncthreads();

  // GEMM2: G = gelu(Y @ red_w^T + red_b); waves 0-1 own rows [w*16, w*16+16)
  if (wave < 2){
    f32x4 acc2[3];
    #pragma unroll
    for (int nf=0;nf<3;nf++) acc2[nf] = (f32x4){0.f,0.f,0.f,0.f};
    const int rowY = wave*16 + lr;
    const int keyY = (rowY&7)<<4;
    #pragma unroll
    for (int kk=0; kk<8; ++kk){
      bf16x8 a2 = *(const bf16x8*)(sm + ((rowY*512 + kk*64 + lk*16) ^ keyY));
      #pragma unroll
      for (int nf=0; nf<3; ++nf){
        bf16x8 b2 = *(const bf16x8*)(W_red + (size_t)(nf*16+lr)*256 + kk*32 + lk*8);
        acc2[nf] = __builtin_amdgcn_mfma_f32_16x16x32_bf16(a2, b2, acc2[nf], 0,0,0);
      }
    }
    #pragma unroll
    for (int nf=0; nf<3; ++nf){
      float rb = red_b[nf*16+lr];
      #pragma unroll
      for (int reg=0; reg<4; ++reg){
        int grow = m0 + wave*16 + lk*4 + reg;
        G[(size_t)grow*RDIM + nf*16 + lr] = gelu_f(acc2[nf][reg] + rb);
      }
    }
  }
}

// ---------------- head: pool + 16 residual blocks (bf16 MFMA, K padded to 64) + linear ----------------
__global__ __launch_bounds__(64) void head_kernel(
    const float* __restrict__ G, const float* __restrict__ Gpad,
    const __bf16* __restrict__ W1p, const __bf16* __restrict__ W2p,
    const float* __restrict__ res_b1, const float* __restrict__ res_b2,
    const float* __restrict__ out_w, const float* __restrict__ out_b,
    float* __restrict__ out)
{
  __shared__ __align__(16) char Hs[16*256];  // [16 rows][64 f32], swizzled, cols 48..63 = 0
  __shared__ __align__(16) char Ys[16*256];
  const int t = threadIdx.x;                 // one wave
  const int lr = t & 15, lk = t >> 4;
  const int b0 = blockIdx.x * 16;

  { // zero pad cols 48..63 (stay zero: layers only write cols<48)
    int row = t >> 2, j4 = 12 + (t & 3);
    int off = (row*256 + j4*16) ^ ((row&7)<<5);
    *(f32x4*)(Hs + off) = (f32x4){0,0,0,0};
    *(f32x4*)(Ys + off) = (f32x4){0,0,0,0};
  }

  // pool: H[b][j] = (sum_{c<30} G[b][c][j] + 6*Gpad[j]) / 36
  #pragma unroll
  for (int pp=0; pp<3; ++pp){
    int idx = pp*64 + t;
    int b = idx / 12, j4 = idx - b*12;
    f32x4 s = ((const f32x4*)Gpad)[j4] * 6.0f;
    const float* g = G + ((size_t)(b0+b)*CELLS)*RDIM + j4*4;
    #pragma unroll
    for (int c=0;c<CELLS;c++) s += *(const f32x4*)(g + c*RDIM);
    s *= (1.0f/36.0f);
    *(f32x4*)(Hs + ((b*256 + j4*16) ^ ((b&7)<<5))) = s;
  }
  __syncthreads();

  const int rowA = lr;
  const int keyA = (rowA&7)<<5;
  for (int l=0; l<16; ++l){
    bf16x8 a[2];
    #pragma unroll
    for (int kk=0;kk<2;kk++){
      f32x4 u0 = *(const f32x4*)(Hs + ((rowA*256 + kk*128 + lk*32) ^ keyA));
      f32x4 u1 = *(const f32x4*)(Hs + ((rowA*256 + kk*128 + lk*32 + 16) ^ keyA));
      a[kk] = pack8(u0,u1);
    }
    #pragma unroll
    for (int nf=0; nf<3; ++nf){
      f32x4 acc = (f32x4){0,0,0,0};
      #pragma unroll
      for (int kk=0;kk<2;kk++){
        bf16x8 bw = *(const bf16x8*)(W1p + ((size_t)l*48 + nf*16 + lr)*64 + kk*32 + lk*8);
        acc = __builtin_amdgcn_mfma_f32_16x16x32_bf16(a[kk], bw, acc, 0,0,0);
      }
      float bj = res_b1[l*48 + nf*16 + lr];
      #pragma unroll
      for (int reg=0; reg<4; ++reg){
        int row = lk*4 + reg;
        *(float*)(Ys + ((row*256 + (nf*16+lr)*4) ^ ((row&7)<<5))) = gelu_f(acc[reg] + bj);
      }
    }
    __syncthreads();
    bf16x8 a2[2];
    #pragma unroll
    for (int kk=0;kk<2;kk++){
      f32x4 u0 = *(const f32x4*)(Ys + ((rowA*256 + kk*128 + lk*32) ^ keyA));
      f32x4 u1 = *(const f32x4*)(Ys + ((rowA*256 + kk*128 + lk*32 + 16) ^ keyA));
      a2[kk] = pack8(u0,u1);
    }
    #pragma unroll
    for (int nf=0; nf<3; ++nf){
      f32x4 acc = (f32x4){0,0,0,0};
      #pragma unroll
      for (int kk=0;kk<2;kk++){
        bf16x8 bw = *(const bf16x8*)(W2p + ((size_t)l*48 + nf*16 + lr)*64 + kk*32 + lk*8);
        acc = __builtin_amdgcn_mfma_f32_16x16x32_bf16(a2[kk], bw, acc, 0,0,0);
      }
      float bj = res_b2[l*48 + nf*16 + lr];
      #pragma unroll
      for (int reg=0; reg<4; ++reg){
        int row = lk*4 + reg;
        float* hp = (float*)(Hs + ((row*256 + (nf*16+lr)*4) ^ ((row&7)<<5)));
        *hp += acc[reg] + bj;
      }
    }
    __syncthreads();
  }

  float s = 0.f;
  #pragma unroll
  for (int i=0;i<12;i++){
    int j = lk*12 + i;
    s += *(const float*)(Hs + ((lr*256 + j*4) ^ ((lr&7)<<5))) * out_w[j];
  }
  s += __shfl_xor(s, 16);
  s += __shfl_xor(s, 32);
  if (lk == 0) out[b0 + lr] = s + out_b[0];
}

extern "C" void kernel_launch(void* const* d_in, const int* in_sizes, int n_in,
                              void* d_out, int out_size, void* d_ws, size_t ws_size,
                              hipStream_t stream) {
  const float* X      = (const float*)d_in[0];
  const float* P      = (const float*)d_in[1];
  const float* conv_w = (const float*)d_in[2];
  const float* conv_b = (const float*)d_in[3];
  const float* red_w  = (const float*)d_in[4];
  const float* red_b  = (const float*)d_in[5];
  const float* res_w1 = (const float*)d_in[6];
  const float* res_b1 = (const float*)d_in[7];
  const float* res_w2 = (const float*)d_in[8];
  const float* res_b2 = (const float*)d_in[9];
  const float* out_w  = (const float*)d_in[10];
  const float* out_b  = (const float*)d_in[11];
  float* out = (float*)d_out;

  char* ws = (char*)d_ws;
  __bf16* W_bt  = (__bf16*)(ws);             // 524288 B
  __bf16* W_red = (__bf16*)(ws + 524288);    // 24576 B
  __bf16* W1p   = (__bf16*)(ws + 548864);    // 98304 B
  __bf16* W2p   = (__bf16*)(ws + 647168);    // 98304 B
  float*  Gpad  = (float*)(ws + 745472);     // 192 B
  float*  G     = (float*)(ws + 1048576);    // 23.6 MB

  prep_kernel<<<290, 256, 0, stream>>>(conv_w, conv_b, P, red_w, red_b, res_w1, res_w2,
                                       W_bt, W_red, W1p, W2p, Gpad);
  main_kernel<<<MAIN_BLOCKS, 256, 0, stream>>>(X, W_bt, conv_b, W_red, red_b, G);
  head_kernel<<<BQ/16, 64, 0, stream>>>(G, Gpad, W1p, W2p, res_b1, res_b2, out_w, out_b, out);
}

// Round 11
// 335.879 us; speedup vs baseline: 1.3327x; 1.1397x over previous
//
#include <hip/hip_runtime.h>
#include <hip/hip_bf16.h>

#define SEQ 120
#define CELLS 30          // real cells (ci<5); row ci=5 is pad-only, precomputed
#define RDIM 48
#define BQ 4096
#define MTOT (BQ*CELLS)           // 122880
#define MAIN_BLOCKS (MTOT/64)     // 1920

typedef __bf16 bf16x8 __attribute__((ext_vector_type(8)));
typedef float  f32x4  __attribute__((ext_vector_type(4)));

__device__ __forceinline__ float gelu_f(float x){
  return 0.5f * x * (1.0f + erff(x * 0.7071067811865476f));
}
__device__ __forceinline__ bf16x8 pack8(f32x4 a, f32x4 b){
  bf16x8 r;
  r[0]=(__bf16)a[0]; r[1]=(__bf16)a[1]; r[2]=(__bf16)a[2]; r[3]=(__bf16)a[3];
  r[4]=(__bf16)b[0]; r[5]=(__bf16)b[1]; r[6]=(__bf16)b[2]; r[7]=(__bf16)b[3];
  return r;
}

// ---------------- prep: weight repack (fp32->bf16) + pad-cell readout Gpad ----------------
__global__ void prep_kernel(const float* __restrict__ conv_w, const float* __restrict__ conv_b,
                            const float* __restrict__ P,
                            const float* __restrict__ red_w, const float* __restrict__ red_b,
                            const float* __restrict__ res_w1, const float* __restrict__ res_w2,
                            __bf16* __restrict__ W_bt, __bf16* __restrict__ W_red,
                            __bf16* __restrict__ W1p, __bf16* __restrict__ W2p,
                            float* __restrict__ Gpad)
{
  const int b = blockIdx.x, t = threadIdx.x;
  if (b < 256){
    // W_bt[o][k], k = pos*256 + c  (pos = kh*2+kw)
    #pragma unroll
    for (int u=0;u<4;u++){
      int k = u*256 + t;
      W_bt[b*1024 + k] = (__bf16)conv_w[b*1024 + (k&255)*4 + (k>>8)];
    }
  } else if (b == 256){
    for (int i=t; i<48*256; i+=256) W_red[i] = (__bf16)red_w[i];
  } else if (b < 273){
    int l = b - 257;
    #pragma unroll
    for (int u=0;u<12;u++){
      int idx = u*256 + t;               // j*64 + k
      int j = idx >> 6, k = idx & 63;
      W1p[l*3072 + idx] = (k < 48) ? (__bf16)res_w1[(l*48+j)*48 + k] : (__bf16)0.0f;
    }
  } else if (b < 289){
    int l = b - 273;
    #pragma unroll
    for (int u=0;u<12;u++){
      int idx = u*256 + t;
      int j = idx >> 6, k = idx & 63;
      W2p[l*3072 + idx] = (k < 48) ? (__bf16)res_w2[(l*48+j)*48 + k] : (__bf16)0.0f;
    }
  } else {
    // Gpad: full fp32 readout of the all-pad patch (all 4 positions = P)
    __shared__ float tg[256];
    float z = conv_b[t];
    for (int c=0;c<256;c++){
      const float* w = conv_w + t*1024 + c*4;
      z += (w[0]+w[1]+w[2]+w[3]) * P[c];
    }
    tg[t] = gelu_f(z);
    __syncthreads();
    if (t < 48){
      float g = red_b[t];
      for (int o=0;o<256;o++) g += red_w[t*256+o]*tg[o];
      Gpad[t] = gelu_f(g);
    }
  }
}

// ---------------- main: VGPR-pend pipelined pos-phase GEMM (M=122880,N=256,K=1024)
//   4 phases (one conv position, BK=256). Phase p+1's A (1KB-contiguous tokens, 256B/lane,
//   16 float4) is ISSUED AT PHASE TOP and stays in flight through the whole compute(p) —
//   FIFO-forced early completion is harmless for registers (no slot hazard). Single 32KB
//   bf16 A-slot in LDS (dbuf lives in VGPRs) -> 2 blocks/CU; B per-wave from L2-resident W_bt.
//   + gelu + fused 256->48 GEMM + gelu -> G ----------------
__global__ __launch_bounds__(256, 2) void main_kernel(
    const float* __restrict__ X, const __bf16* __restrict__ W_bt,
    const float* __restrict__ conv_b, const __bf16* __restrict__ W_red,
    const float* __restrict__ red_b, float* __restrict__ G)
{
  // LDS: A bf16 [64 rows][512B] = 32KB (one phase); Y bf16 [64][512B] reuses same region
  __shared__ __align__(16) char sm[32768];
  const int tid  = threadIdx.x;
  const int lane = tid & 63;
  const int wave = tid >> 6;                 // 0..3; wave owns 64 B-cols AND stages rows [w*16,w*16+16)
  const int lr = lane & 15, lk = lane >> 4;
  const int m0 = blockIdx.x * 64;

  // pend source: lane (lr,lk) covers row wave*16+lr, byte-quarter lk*256 of the row's 1KB token
  const int srow_r = wave*16 + lr;
  const char* srow;
  {
    int m = m0 + srow_r;
    int bs = m / 30;
    int cs = m - bs*30;
    int ci = cs/6, cj = cs - ci*6;           // ci<5 => all 4 tokens < 120
    srow = (const char*)(X + ((size_t)bs*SEQ + 24*ci + 2*cj)*256) + lk*256;
  }
  const __bf16* bbase[4];
  #pragma unroll
  for (int ni=0; ni<4; ++ni)
    bbase[ni] = W_bt + (size_t)(wave*64 + ni*16 + lr)*1024 + lk*8;

  f32x4 acc[4][4];
  #pragma unroll
  for (int a=0;a<4;a++)
    #pragma unroll
    for (int b=0;b<4;b++) acc[a][b] = (f32x4){0.f,0.f,0.f,0.f};

  f32x4 pend[16];                            // 64 VGPR: lane's 256B of next phase's A
  // token byte-offset for position p: ((p>>1)*12 + (p&1)) * 1024
  auto LOADPEND = [&](int p){
    const int off = ((p>>1)*12 + (p&1)) << 10;
    #pragma unroll
    for (int i=0;i<16;i++) pend[i] = *(const f32x4*)(srow + off + i*16);
  };
  // cvt pend -> A-slot: row srow_r, byte cols [lk*128, lk*128+128), XOR-swizzled
  auto CVTW = [&](){
    const int key = (srow_r&7)<<4;
    #pragma unroll
    for (int j=0;j<8;j++)
      *(bf16x8*)(sm + srow_r*512 + ((lk*128 + j*16) ^ key)) = pack8(pend[2*j], pend[2*j+1]);
  };

  LOADPEND(0);
  CVTW();
  __syncthreads();

  for (int p=0; p<4; ++p){
    if (p < 3) LOADPEND(p+1);                // issue-early: in flight across entire compute(p)
    #pragma unroll
    for (int ls=0; ls<4; ++ls){
      #pragma unroll
      for (int ks=0; ks<2; ++ks){
        bf16x8 bv[4];
        #pragma unroll
        for (int ni=0; ni<4; ++ni)
          bv[ni] = *(const bf16x8*)(bbase[ni] + p*256 + ls*64 + ks*32);
        bf16x8 av[4];
        #pragma unroll
        for (int mi=0; mi<4; ++mi){
          int row = mi*16 + lr;
          av[mi] = *(const bf16x8*)(sm + row*512 + ((ls*128 + ks*64 + lk*16) ^ ((row&7)<<4)));
        }
        #pragma unroll
        for (int mi=0; mi<4; ++mi)
          #pragma unroll
          for (int ni=0; ni<4; ++ni)
            acc[mi][ni] = __builtin_amdgcn_mfma_f32_16x16x32_bf16(av[mi], bv[ni], acc[mi][ni], 0,0,0);
      }
    }
    __syncthreads();                         // all waves done reading slot(p)
    if (p < 3){
      CVTW();                                // write phase p+1 into the slot
      __syncthreads();
    }
  }

  // epilogue 1: conv bias + gelu -> Y bf16 [64][512B] in LDS (row-swizzled), reuses slot
  #pragma unroll
  for (int ni=0; ni<4; ++ni){
    const int col = wave*64 + ni*16 + lr;
    const float cb = conv_b[col];
    #pragma unroll
    for (int mi=0; mi<4; ++mi){
      #pragma unroll
      for (int reg=0; reg<4; ++reg){
        int row = mi*16 + lk*4 + reg;
        float y = gelu_f(acc[mi][ni][reg] + cb);
        *(__bf16*)(sm + ((row*512 + col*2) ^ ((row&7)<<4))) = (__bf16)y;
      }
    }
  }
  __syncthreads();

  // GEMM2: G = gelu(Y @ red_w^T + red_b); wave w owns rows [w*16, w*16+16)
  f32x4 acc2[3];
  #pragma unroll
  for (int nf=0;nf<3;nf++) acc2[nf] = (f32x4){0.f,0.f,0.f,0.f};
  const int rowY = wave*16 + lr;
  const int keyY = (rowY&7)<<4;
  #pragma unroll
  for (int kk=0; kk<8; ++kk){
    bf16x8 a2 = *(const bf16x8*)(sm + ((rowY*512 + kk*64 + lk*16) ^ keyY));
    #pragma unroll
    for (int nf=0; nf<3; ++nf){
      bf16x8 b2 = *(const bf16x8*)(W_red + (size_t)(nf*16+lr)*256 + kk*32 + lk*8);
      acc2[nf] = __builtin_amdgcn_mfma_f32_16x16x32_bf16(a2, b2, acc2[nf], 0,0,0);
    }
  }
  #pragma unroll
  for (int nf=0; nf<3; ++nf){
    float rb = red_b[nf*16+lr];
    #pragma unroll
    for (int reg=0; reg<4; ++reg){
      int grow = m0 + wave*16 + lk*4 + reg;
      G[(size_t)grow*RDIM + nf*16 + lr] = gelu_f(acc2[nf][reg] + rb);
    }
  }
}

// ---------------- head: pool + 16 residual blocks (bf16 MFMA, K padded to 64) + linear ----------------
__global__ __launch_bounds__(64) void head_kernel(
    const float* __restrict__ G, const float* __restrict__ Gpad,
    const __bf16* __restrict__ W1p, const __bf16* __restrict__ W2p,
    const float* __restrict__ res_b1, const float* __restrict__ res_b2,
    const float* __restrict__ out_w, const float* __restrict__ out_b,
    float* __restrict__ out)
{
  __shared__ __align__(16) char Hs[16*256];  // [16 rows][64 f32], swizzled, cols 48..63 = 0
  __shared__ __align__(16) char Ys[16*256];
  const int t = threadIdx.x;                 // one wave
  const int lr = t & 15, lk = t >> 4;
  const int b0 = blockIdx.x * 16;

  { // zero pad cols 48..63 (stay zero: layers only write cols<48)
    int row = t >> 2, j4 = 12 + (t & 3);
    int off = (row*256 + j4*16) ^ ((row&7)<<5);
    *(f32x4*)(Hs + off) = (f32x4){0,0,0,0};
    *(f32x4*)(Ys + off) = (f32x4){0,0,0,0};
  }

  // pool: H[b][j] = (sum_{c<30} G[b][c][j] + 6*Gpad[j]) / 36
  #pragma unroll
  for (int pp=0; pp<3; ++pp){
    int idx = pp*64 + t;
    int b = idx / 12, j4 = idx - b*12;
    f32x4 s = ((const f32x4*)Gpad)[j4] * 6.0f;
    const float* g = G + ((size_t)(b0+b)*CELLS)*RDIM + j4*4;
    #pragma unroll
    for (int c=0;c<CELLS;c++) s += *(const f32x4*)(g + c*RDIM);
    s *= (1.0f/36.0f);
    *(f32x4*)(Hs + ((b*256 + j4*16) ^ ((b&7)<<5))) = s;
  }
  __syncthreads();

  const int rowA = lr;
  const int keyA = (rowA&7)<<5;
  for (int l=0; l<16; ++l){
    bf16x8 a[2];
    #pragma unroll
    for (int kk=0;kk<2;kk++){
      f32x4 u0 = *(const f32x4*)(Hs + ((rowA*256 + kk*128 + lk*32) ^ keyA));
      f32x4 u1 = *(const f32x4*)(Hs + ((rowA*256 + kk*128 + lk*32 + 16) ^ keyA));
      a[kk] = pack8(u0,u1);
    }
    #pragma unroll
    for (int nf=0; nf<3; ++nf){
      f32x4 acc = (f32x4){0,0,0,0};
      #pragma unroll
      for (int kk=0;kk<2;kk++){
        bf16x8 bw = *(const bf16x8*)(W1p + ((size_t)l*48 + nf*16 + lr)*64 + kk*32 + lk*8);
        acc = __builtin_amdgcn_mfma_f32_16x16x32_bf16(a[kk], bw, acc, 0,0,0);
      }
      float bj = res_b1[l*48 + nf*16 + lr];
      #pragma unroll
      for (int reg=0; reg<4; ++reg){
        int row = lk*4 + reg;
        *(float*)(Ys + ((row*256 + (nf*16+lr)*4) ^ ((row&7)<<5))) = gelu_f(acc[reg] + bj);
      }
    }
    __syncthreads();
    bf16x8 a2[2];
    #pragma unroll
    for (int kk=0;kk<2;kk++){
      f32x4 u0 = *(const f32x4*)(Ys + ((rowA*256 + kk*128 + lk*32) ^ keyA));
      f32x4 u1 = *(const f32x4*)(Ys + ((rowA*256 + kk*128 + lk*32 + 16) ^ keyA));
      a2[kk] = pack8(u0,u1);
    }
    #pragma unroll
    for (int nf=0; nf<3; ++nf){
      f32x4 acc = (f32x4){0,0,0,0};
      #pragma unroll
      for (int kk=0;kk<2;kk++){
        bf16x8 bw = *(const bf16x8*)(W2p + ((size_t)l*48 + nf*16 + lr)*64 + kk*32 + lk*8);
        acc = __builtin_amdgcn_mfma_f32_16x16x32_bf16(a2[kk], bw, acc, 0,0,0);
      }
      float bj = res_b2[l*48 + nf*16 + lr];
      #pragma unroll
      for (int reg=0; reg<4; ++reg){
        int row = lk*4 + reg;
        float* hp = (float*)(Hs + ((row*256 + (nf*16+lr)*4) ^ ((row&7)<<5)));
        *hp += acc[reg] + bj;
      }
    }
    __syncthreads();
  }

  float s = 0.f;
  #pragma unroll
  for (int i=0;i<12;i++){
    int j = lk*12 + i;
    s += *(const float*)(Hs + ((lr*256 + j*4) ^ ((lr&7)<<5))) * out_w[j];
  }
  s += __shfl_xor(s, 16);
  s += __shfl_xor(s, 32);
  if (lk == 0) out[b0 + lr] = s + out_b[0];
}

extern "C" void kernel_launch(void* const* d_in, const int* in_sizes, int n_in,
                              void* d_out, int out_size, void* d_ws, size_t ws_size,
                              hipStream_t stream) {
  const float* X      = (const float*)d_in[0];
  const float* P      = (const float*)d_in[1];
  const float* conv_w = (const float*)d_in[2];
  const float* conv_b = (const float*)d_in[3];
  const float* red_w  = (const float*)d_in[4];
  const float* red_b  = (const float*)d_in[5];
  const float* res_w1 = (const float*)d_in[6];
  const float* res_b1 = (const float*)d_in[7];
  const float* res_w2 = (const float*)d_in[8];
  const float* res_b2 = (const float*)d_in[9];
  const float* out_w  = (const float*)d_in[10];
  const float* out_b  = (const float*)d_in[11];
  float* out = (float*)d_out;

  char* ws = (char*)d_ws;
  __bf16* W_bt  = (__bf16*)(ws);             // 524288 B
  __bf16* W_red = (__bf16*)(ws + 524288);    // 24576 B
  __bf16* W1p   = (__bf16*)(ws + 548864);    // 98304 B
  __bf16* W2p   = (__bf16*)(ws + 647168);    // 98304 B
  float*  Gpad  = (float*)(ws + 745472);     // 192 B
  float*  G     = (float*)(ws + 1048576);    // 23.6 MB

  prep_kernel<<<290, 256, 0, stream>>>(conv_w, conv_b, P, red_w, red_b, res_w1, res_w2,
                                       W_bt, W_red, W1p, W2p, Gpad);
  main_kernel<<<MAIN_BLOCKS, 256, 0, stream>>>(X, W_bt, conv_b, W_red, red_b, G);
  head_kernel<<<BQ/16, 64, 0, stream>>>(G, Gpad, W1p, W2p, res_b1, res_b2, out_w, out_b, out);
}

// Round 12
// 268.423 us; speedup vs baseline: 1.6677x; 1.2513x over previous
//
#include <hip/hip_runtime.h>
#include <hip/hip_bf16.h>

#define SEQ 120
#define CELLS 30          // real cells (ci<5); row ci=5 is pad-only, precomputed
#define RDIM 48
#define BQ 4096
#define MTOT (BQ*CELLS)           // 122880
#define MAIN_BLOCKS (MTOT/64)     // 1920

typedef __bf16 bf16x8 __attribute__((ext_vector_type(8)));
typedef float  f32x4  __attribute__((ext_vector_type(4)));

__device__ __forceinline__ float gelu_f(float x){
  return 0.5f * x * (1.0f + erff(x * 0.7071067811865476f));
}
__device__ __forceinline__ bf16x8 pack8(f32x4 a, f32x4 b){
  bf16x8 r;
  r[0]=(__bf16)a[0]; r[1]=(__bf16)a[1]; r[2]=(__bf16)a[2]; r[3]=(__bf16)a[3];
  r[4]=(__bf16)b[0]; r[5]=(__bf16)b[1]; r[6]=(__bf16)b[2]; r[7]=(__bf16)b[3];
  return r;
}

// ---------------- prep: weight repack (fp32->bf16) + pad-cell readout Gpad ----------------
__global__ void prep_kernel(const float* __restrict__ conv_w, const float* __restrict__ conv_b,
                            const float* __restrict__ P,
                            const float* __restrict__ red_w, const float* __restrict__ red_b,
                            const float* __restrict__ res_w1, const float* __restrict__ res_w2,
                            __bf16* __restrict__ W_bt, __bf16* __restrict__ W_red,
                            __bf16* __restrict__ W1p, __bf16* __restrict__ W2p,
                            float* __restrict__ Gpad)
{
  const int b = blockIdx.x, t = threadIdx.x;
  if (b < 256){
    // W_bt[o][k], k = pos*256 + c  (pos = kh*2+kw)
    #pragma unroll
    for (int u=0;u<4;u++){
      int k = u*256 + t;
      W_bt[b*1024 + k] = (__bf16)conv_w[b*1024 + (k&255)*4 + (k>>8)];
    }
  } else if (b == 256){
    for (int i=t; i<48*256; i+=256) W_red[i] = (__bf16)red_w[i];
  } else if (b < 273){
    int l = b - 257;
    #pragma unroll
    for (int u=0;u<12;u++){
      int idx = u*256 + t;               // j*64 + k
      int j = idx >> 6, k = idx & 63;
      W1p[l*3072 + idx] = (k < 48) ? (__bf16)res_w1[(l*48+j)*48 + k] : (__bf16)0.0f;
    }
  } else if (b < 289){
    int l = b - 273;
    #pragma unroll
    for (int u=0;u<12;u++){
      int idx = u*256 + t;
      int j = idx >> 6, k = idx & 63;
      W2p[l*3072 + idx] = (k < 48) ? (__bf16)res_w2[(l*48+j)*48 + k] : (__bf16)0.0f;
    }
  } else {
    // Gpad: full fp32 readout of the all-pad patch (all 4 positions = P)
    __shared__ float tg[256];
    float z = conv_b[t];
    for (int c=0;c<256;c++){
      const float* w = conv_w + t*1024 + c*4;
      z += (w[0]+w[1]+w[2]+w[3]) * P[c];
    }
    tg[t] = gelu_f(z);
    __syncthreads();
    if (t < 48){
      float g = red_b[t];
      for (int o=0;o<256;o++) g += red_w[t*256+o]*tg[o];
      Gpad[t] = gelu_f(g);
    }
  }
}

// ---------------- main: no-vmem-in-compute pipelined GEMM (M=122880,N=256,K=1024)
//   16 phases of BK=64. Per phase: APL(s+2) A->VGPR (in flight through compute),
//   CVTW(s+1) cvt->A-dbuf LDS, COMPUTE(s) pure ds_read+MFMA (no vmcnt waits inside),
//   BGLL(s+1) B-slab->LDS dbuf AFTER compute (avoids compiler gll->ds_read vmcnt stall),
//   one __syncthreads per phase (drains both prefetch streams after a full compute of cover).
//   LDS 80KB -> 2 blocks/CU. + gelu + fused 256->48 GEMM + gelu -> G ----------------
__global__ __launch_bounds__(256, 2) void main_kernel(
    const float* __restrict__ X, const __bf16* __restrict__ W_bt,
    const float* __restrict__ conv_b, const __bf16* __restrict__ W_red,
    const float* __restrict__ red_b, float* __restrict__ G)
{
  // LDS: Abuf [2][64][128B] = 16KB at [0,16K); Bbuf [2][256][128B] = 64KB at [16K,80K)
  // Y bf16 [64][512B] = 32KB reuses [0,32K) after the K-loop.
  __shared__ __align__(16) char sm[81920];
  const int tid  = threadIdx.x;
  const int lane = tid & 63;
  const int wave = tid >> 6;                 // 0..3; wave owns 64 B-cols
  const int lr = lane & 15, lk = lane >> 4;
  const int m0 = blockIdx.x * 64;

  // A staging role: thread covers row r, 64B quarter q of the row's per-phase 256B
  const int r = tid >> 2, q = tid & 3;
  const char* rowb;
  {
    int m = m0 + r;
    int bs = m / 30;
    int cs = m - bs*30;
    int ci = cs/6, cj = cs - ci*6;           // ci<5 => all 4 tokens < 120
    rowb = (const char*)(X + ((size_t)bs*SEQ + 24*ci + 2*cj)*256) + q*64;
  }
  // B staging role: wave w, instr j: cols w*64+j*8+(lane>>3); src chunk pre-swizzled (m173)
  const char* bsrc = (const char*)W_bt + (size_t)(wave*64 + (lane>>3))*2048
                     + (size_t)(((lane&7) ^ (lane>>3))*16);
  const int bdst = wave*64*128 + lane*16;    // + j*1024 within Bbuf slot

  f32x4 acc[4][4];
  #pragma unroll
  for (int a=0;a<4;a++)
    #pragma unroll
    for (int b=0;b<4;b++) acc[a][b] = (f32x4){0.f,0.f,0.f,0.f};

  f32x4 pe[4], po[4];                        // two named pend slots (static indexing)

  // A global bytes for phase s: pos p=s>>2 -> token ((p>>1)*12+(p&1)); quarter (s&3)*256
  auto APL = [&](int s, f32x4* p){
    const int off = (((s>>3)*12 + ((s>>2)&1)) << 10) + ((s&3) << 8);
    #pragma unroll
    for (int i=0;i<4;i++) p[i] = *(const f32x4*)(rowb + off + i*16);
  };
  auto CVTW = [&](int slot, const f32x4* p){
    const int key = (r&7)<<4;
    char* base = sm + slot*8192 + r*128;
    *(bf16x8*)(base + ((q*32     ) ^ key)) = pack8(p[0], p[1]);
    *(bf16x8*)(base + ((q*32 + 16) ^ key)) = pack8(p[2], p[3]);
  };
  auto BGLL = [&](int s, int slot){
    char* dst = sm + 16384 + slot*32768 + bdst;
    const char* src = bsrc + s*128;
    #pragma unroll
    for (int j=0;j<8;j++){
      __builtin_amdgcn_global_load_lds(
        (const __attribute__((address_space(1))) void*)(src + (size_t)j*8*2048),
        (__attribute__((address_space(3))) void*)(dst + j*1024),
        16, 0, 0);
    }
  };
  auto COMPUTE = [&](int s){
    const int slot = s&1;
    #pragma unroll
    for (int ks=0; ks<2; ++ks){
      bf16x8 bv[4];
      #pragma unroll
      for (int ni=0; ni<4; ++ni){
        int col = wave*64 + ni*16 + lr;
        bv[ni] = *(const bf16x8*)(sm + 16384 + slot*32768 + col*128
                                  + ((ks*64 + lk*16) ^ ((col&7)<<4)));
      }
      bf16x8 av[4];
      #pragma unroll
      for (int mi=0; mi<4; ++mi){
        int row = mi*16 + lr;
        av[mi] = *(const bf16x8*)(sm + slot*8192 + row*128
                                  + ((ks*64 + lk*16) ^ ((row&7)<<4)));
      }
      #pragma unroll
      for (int mi=0; mi<4; ++mi)
        #pragma unroll
        for (int ni=0; ni<4; ++ni)
          acc[mi][ni] = __builtin_amdgcn_mfma_f32_16x16x32_bf16(av[mi], bv[ni], acc[mi][ni], 0,0,0);
    }
  };

  // prologue: A(0)->Abuf0, A(1)->po, B(0)->Bbuf0
  APL(0, pe); CVTW(0, pe);
  APL(1, po);
  BGLL(0, 0);
  __syncthreads();

  for (int s=0; s<16; s+=2){
    // even phase s: consume po=A(s+1), refill pe=A(s+2)
    CVTW(1, po);                             // s+1 <= 15 always here
    if (s+2 < 16) APL(s+2, pe);
    COMPUTE(s);
    BGLL(s+1, 1);                            // after compute: no gll->ds_read stall in MFMAs
    __syncthreads();
    // odd phase s+1: consume pe=A(s+2), refill po=A(s+3)
    if (s+2 < 16) CVTW(0, pe);
    if (s+3 < 16) APL(s+3, po);
    COMPUTE(s+1);
    if (s+2 < 16) BGLL(s+2, 0);
    __syncthreads();
  }

  // epilogue 1: conv bias + gelu -> Y bf16 [64][512B] in LDS (row-swizzled), reuses [0,32K)
  #pragma unroll
  for (int ni=0; ni<4; ++ni){
    const int col = wave*64 + ni*16 + lr;
    const float cb = conv_b[col];
    #pragma unroll
    for (int mi=0; mi<4; ++mi){
      #pragma unroll
      for (int reg=0; reg<4; ++reg){
        int row = mi*16 + lk*4 + reg;
        float y = gelu_f(acc[mi][ni][reg] + cb);
        *(__bf16*)(sm + ((row*512 + col*2) ^ ((row&7)<<4))) = (__bf16)y;
      }
    }
  }
  __syncthreads();

  // GEMM2: G = gelu(Y @ red_w^T + red_b); wave w owns rows [w*16, w*16+16)
  f32x4 acc2[3];
  #pragma unroll
  for (int nf=0;nf<3;nf++) acc2[nf] = (f32x4){0.f,0.f,0.f,0.f};
  const int rowY = wave*16 + lr;
  const int keyY = (rowY&7)<<4;
  #pragma unroll
  for (int kk=0; kk<8; ++kk){
    bf16x8 a2 = *(const bf16x8*)(sm + ((rowY*512 + kk*64 + lk*16) ^ keyY));
    #pragma unroll
    for (int nf=0; nf<3; ++nf){
      bf16x8 b2 = *(const bf16x8*)(W_red + (size_t)(nf*16+lr)*256 + kk*32 + lk*8);
      acc2[nf] = __builtin_amdgcn_mfma_f32_16x16x32_bf16(a2, b2, acc2[nf], 0,0,0);
    }
  }
  #pragma unroll
  for (int nf=0; nf<3; ++nf){
    float rb = red_b[nf*16+lr];
    #pragma unroll
    for (int reg=0; reg<4; ++reg){
      int grow = m0 + wave*16 + lk*4 + reg;
      G[(size_t)grow*RDIM + nf*16 + lr] = gelu_f(acc2[nf][reg] + rb);
    }
  }
}

// ---------------- head: pool + 16 residual blocks (bf16 MFMA, K padded to 64) + linear ----------------
__global__ __launch_bounds__(64) void head_kernel(
    const float* __restrict__ G, const float* __restrict__ Gpad,
    const __bf16* __restrict__ W1p, const __bf16* __restrict__ W2p,
    const float* __restrict__ res_b1, const float* __restrict__ res_b2,
    const float* __restrict__ out_w, const float* __restrict__ out_b,
    float* __restrict__ out)
{
  __shared__ __align__(16) char Hs[16*256];  // [16 rows][64 f32], swizzled, cols 48..63 = 0
  __shared__ __align__(16) char Ys[16*256];
  const int t = threadIdx.x;                 // one wave
  const int lr = t & 15, lk = t >> 4;
  const int b0 = blockIdx.x * 16;

  { // zero pad cols 48..63 (stay zero: layers only write cols<48)
    int row = t >> 2, j4 = 12 + (t & 3);
    int off = (row*256 + j4*16) ^ ((row&7)<<5);
    *(f32x4*)(Hs + off) = (f32x4){0,0,0,0};
    *(f32x4*)(Ys + off) = (f32x4){0,0,0,0};
  }

  // pool: H[b][j] = (sum_{c<30} G[b][c][j] + 6*Gpad[j]) / 36
  #pragma unroll
  for (int pp=0; pp<3; ++pp){
    int idx = pp*64 + t;
    int b = idx / 12, j4 = idx - b*12;
    f32x4 s = ((const f32x4*)Gpad)[j4] * 6.0f;
    const float* g = G + ((size_t)(b0+b)*CELLS)*RDIM + j4*4;
    #pragma unroll
    for (int c=0;c<CELLS;c++) s += *(const f32x4*)(g + c*RDIM);
    s *= (1.0f/36.0f);
    *(f32x4*)(Hs + ((b*256 + j4*16) ^ ((b&7)<<5))) = s;
  }
  __syncthreads();

  const int rowA = lr;
  const int keyA = (rowA&7)<<5;
  for (int l=0; l<16; ++l){
    bf16x8 a[2];
    #pragma unroll
    for (int kk=0;kk<2;kk++){
      f32x4 u0 = *(const f32x4*)(Hs + ((rowA*256 + kk*128 + lk*32) ^ keyA));
      f32x4 u1 = *(const f32x4*)(Hs + ((rowA*256 + kk*128 + lk*32 + 16) ^ keyA));
      a[kk] = pack8(u0,u1);
    }
    #pragma unroll
    for (int nf=0; nf<3; ++nf){
      f32x4 acc = (f32x4){0,0,0,0};
      #pragma unroll
      for (int kk=0;kk<2;kk++){
        bf16x8 bw = *(const bf16x8*)(W1p + ((size_t)l*48 + nf*16 + lr)*64 + kk*32 + lk*8);
        acc = __builtin_amdgcn_mfma_f32_16x16x32_bf16(a[kk], bw, acc, 0,0,0);
      }
      float bj = res_b1[l*48 + nf*16 + lr];
      #pragma unroll
      for (int reg=0; reg<4; ++reg){
        int row = lk*4 + reg;
        *(float*)(Ys + ((row*256 + (nf*16+lr)*4) ^ ((row&7)<<5))) = gelu_f(acc[reg] + bj);
      }
    }
    __syncthreads();
    bf16x8 a2[2];
    #pragma unroll
    for (int kk=0;kk<2;kk++){
      f32x4 u0 = *(const f32x4*)(Ys + ((rowA*256 + kk*128 + lk*32) ^ keyA));
      f32x4 u1 = *(const f32x4*)(Ys + ((rowA*256 + kk*128 + lk*32 + 16) ^ keyA));
      a2[kk] = pack8(u0,u1);
    }
    #pragma unroll
    for (int nf=0; nf<3; ++nf){
      f32x4 acc = (f32x4){0,0,0,0};
      #pragma unroll
      for (int kk=0;kk<2;kk++){
        bf16x8 bw = *(const bf16x8*)(W2p + ((size_t)l*48 + nf*16 + lr)*64 + kk*32 + lk*8);
        acc = __builtin_amdgcn_mfma_f32_16x16x32_bf16(a2[kk], bw, acc, 0,0,0);
      }
      float bj = res_b2[l*48 + nf*16 + lr];
      #pragma unroll
      for (int reg=0; reg<4; ++reg){
        int row = lk*4 + reg;
        float* hp = (float*)(Hs + ((row*256 + (nf*16+lr)*4) ^ ((row&7)<<5)));
        *hp += acc[reg] + bj;
      }
    }
    __syncthreads();
  }

  float s = 0.f;
  #pragma unroll
  for (int i=0;i<12;i++){
    int j = lk*12 + i;
    s += *(const float*)(Hs + ((lr*256 + j*4) ^ ((lr&7)<<5))) * out_w[j];
  }
  s += __shfl_xor(s, 16);
  s += __shfl_xor(s, 32);
  if (lk == 0) out[b0 + lr] = s + out_b[0];
}

extern "C" void kernel_launch(void* const* d_in, const int* in_sizes, int n_in,
                              void* d_out, int out_size, void* d_ws, size_t ws_size,
                              hipStream_t stream) {
  const float* X      = (const float*)d_in[0];
  const float* P      = (const float*)d_in[1];
  const float* conv_w = (const float*)d_in[2];
  const float* conv_b = (const float*)d_in[3];
  const float* red_w  = (const float*)d_in[4];
  const float* red_b  = (const float*)d_in[5];
  const float* res_w1 = (const float*)d_in[6];
  const float* res_b1 = (const float*)d_in[7];
  const float* res_w2 = (const float*)d_in[8];
  const float* res_b2 = (const float*)d_in[9];
  const float* out_w  = (const float*)d_in[10];
  const float* out_b  = (const float*)d_in[11];
  float* out = (float*)d_out;

  char* ws = (char*)d_ws;
  __bf16* W_bt  = (__bf16*)(ws);             // 524288 B
  __bf16* W_red = (__bf16*)(ws + 524288);    // 24576 B
  __bf16* W1p   = (__bf16*)(ws + 548864);    // 98304 B
  __bf16* W2p   = (__bf16*)(ws + 647168);    // 98304 B
  float*  Gpad  = (float*)(ws + 745472);     // 192 B
  float*  G     = (float*)(ws + 1048576);    // 23.6 MB

  prep_kernel<<<290, 256, 0, stream>>>(conv_w, conv_b, P, red_w, red_b, res_w1, res_w2,
                                       W_bt, W_red, W1p, W2p, Gpad);
  main_kernel<<<MAIN_BLOCKS, 256, 0, stream>>>(X, W_bt, conv_b, W_red, red_b, G);
  head_kernel<<<BQ/16, 64, 0, stream>>>(G, Gpad, W1p, W2p, res_b1, res_b2, out_w, out_b, out);
}